// Round 3
// baseline (582.032 us; speedup 1.0000x reference)
//
#include <hip/hip_runtime.h>
#include <hip/hip_bf16.h>

typedef unsigned short u16;
typedef __bf16 bf16x8 __attribute__((ext_vector_type(8)));
typedef float f32x4 __attribute__((ext_vector_type(4)));

#define BATCH 16
#define C 256
#define NTOK 4096      // H*W
#define CN 1048576     // C*NTOK

__device__ __forceinline__ u16 f2b(float f) {
  __hip_bfloat16 h = __float2bfloat16(f);
  return __builtin_bit_cast(u16, h);
}
__device__ __forceinline__ float b2f(u16 u) {
  unsigned int x = ((unsigned int)u) << 16;
  return __builtin_bit_cast(float, x);
}

// async global->LDS, 16B per lane. LDS dest must be wave-uniform base
// (HW adds lane*16); global src is per-lane.
__device__ __forceinline__ void glds16(const u16* g, u16* l) {
  __builtin_amdgcn_global_load_lds(
      (const __attribute__((address_space(1))) unsigned int*)(g),
      (__attribute__((address_space(3))) unsigned int*)(l), 16, 0, 0);
}

// ---------------------------------------------------------------------------
// prep_x: x f32 [B][C][N] -> xbf [B][C][N], xT [B][N][C]; row partial sums
// atomically into rws (rws zeroed by prep_w, launched before).
// grid (128, 8, B), block 256
__global__ __launch_bounds__(256) void prep_x_kernel(
    const float* __restrict__ x, u16* __restrict__ xbf, u16* __restrict__ xT,
    float* __restrict__ rws) {
  __shared__ float t[32][33];
  int b = blockIdx.z;
  int c0 = blockIdx.y * 32, n0 = blockIdx.x * 32;
  int tid = threadIdx.x;
  int i = tid >> 3, j4 = (tid & 7) * 4;
  const float* xb = x + (long)b * CN;
  float4 v = *(const float4*)(xb + (long)(c0 + i) * NTOK + n0 + j4);
  ushort4 bv;
  bv.x = f2b(v.x); bv.y = f2b(v.y); bv.z = f2b(v.z); bv.w = f2b(v.w);
  *(ushort4*)(xbf + (long)b * CN + (long)(c0 + i) * NTOK + n0 + j4) = bv;
  t[i][j4 + 0] = v.x; t[i][j4 + 1] = v.y; t[i][j4 + 2] = v.z; t[i][j4 + 3] = v.w;
  __syncthreads();
  ushort4 o;
  o.x = f2b(t[j4 + 0][i]); o.y = f2b(t[j4 + 1][i]);
  o.z = f2b(t[j4 + 2][i]); o.w = f2b(t[j4 + 3][i]);
  *(ushort4*)(xT + (long)b * CN + (long)(n0 + i) * C + c0 + j4) = o;
  if (tid < 32) {
    float s = 0.f;
#pragma unroll
    for (int j = 0; j < 32; ++j) s += t[tid][j];
    atomicAdd(&rws[b * C + c0 + tid], s);
  }
}

// ---------------------------------------------------------------------------
// prep_w: bf16-convert weights; WvT transposed; conv w reordered [o][tap][i];
// also zeroes rws and zbuf. grid 3328 x 256.
__global__ __launch_bounds__(256) void prep_w_kernel(
    const float* __restrict__ qkv_w, const float* __restrict__ proj_w,
    const float* __restrict__ conv_w, u16* __restrict__ Wq, u16* __restrict__ Wk,
    u16* __restrict__ WvT, u16* __restrict__ Pw, u16* __restrict__ cw,
    float* __restrict__ rws, u16* __restrict__ zbuf) {
  int idx = blockIdx.x * 256 + threadIdx.x;
  if (idx < 4096) rws[idx] = 0.f;
  if (idx < 256) zbuf[idx] = 0;
  if (idx < 65536) {
    Wq[idx] = f2b(qkv_w[idx]);
  } else if (idx < 131072) {
    int e = idx - 65536;
    Wk[e] = f2b(qkv_w[65536 + e]);
  } else if (idx < 196608) {
    int e = idx - 131072;
    int i = e >> 8, d = e & 255;
    WvT[e] = f2b(qkv_w[131072 + d * 256 + i]);
  } else if (idx < 262144) {
    int e = idx - 196608;
    Pw[e] = f2b(proj_w[e]);
  } else if (idx < 851968) {
    int e = idx - 262144;
    int o = e / 2304;
    int rem = e - o * 2304;
    int tap = rem >> 8, i = rem & 255;
    cw[e] = f2b(conv_w[o * 2304 + i * 9 + tap]);
  }
}

// bias_uw: u[b][d] = Wk[d,:]*r[b,:] ; w[b][c] = Wq[c,:]*r[b,:]
__global__ __launch_bounds__(512) void bias_uw_kernel(
    const float* __restrict__ qkv_w, const float* __restrict__ r,
    float* __restrict__ u, float* __restrict__ w) {
  int b = blockIdx.x, t = threadIdx.x;
  const float* rb = r + b * C;
  if (t < 256) {
    float s = 0.f;
    for (int i = 0; i < C; ++i) s += qkv_w[(256 + t) * 256 + i] * rb[i];
    u[b * C + t] = s;
  } else {
    int c = t - 256;
    float s = 0.f;
    for (int i = 0; i < C; ++i) s += qkv_w[c * 256 + i] * rb[i];
    w[b * C + c] = s;
  }
}

// ---------------------------------------------------------------------------
// Generic GEMM C = A*B^T (both K-contiguous), 128x128 tile, BK=32, 4 waves,
// global_load_lds staging + slot-XOR swizzle, double-buffered.
// grid (tilesM*tilesN, ksplit, batch)
// EPI 0: f32 partial store at (b*gridDim.y+ks)*sC. EPI 1: bf16. EPI 2: S-epi.
template <int EPI>
__global__ __launch_bounds__(256, 2) void gemm_glds_kernel(
    const u16* __restrict__ A, const u16* __restrict__ B, void* __restrict__ Cv,
    int K, int lda, int ldb, int ldc, int tilesN, long sA, long sB, long sC,
    float scale, const float* __restrict__ e1, const float* __restrict__ e2,
    const float* __restrict__ e3, const float* __restrict__ e4, int e34stride) {
  int b = blockIdx.z, ks = blockIdx.y;
  A += (long)b * sA + (long)ks * K;
  B += (long)b * sB + (long)ks * K;
  int ty = blockIdx.x / tilesN, tx = blockIdx.x % tilesN;
  int row0 = ty * 128, col0 = tx * 128;

  __shared__ u16 lA[2][4096];
  __shared__ u16 lB[2][4096];

  int tid = threadIdx.x;
  int lane = tid & 63, wv = tid >> 6;
  int wm = wv >> 1, wn = wv & 1;
  int fr = lane & 15, kq = lane >> 4;
  int kqs = kq ^ ((fr >> 1) & 3);

  // staging chunks: c0 = wv*128+lane, c1 = c0+64 (16B each)
  int c0 = wv * 128 + lane, c1 = c0 + 64;
  int r0s = c0 >> 2, r1s = c1 >> 2;
  int ls0 = (c0 & 3) ^ ((r0s >> 1) & 3);
  int ls1 = (c1 & 3) ^ ((r1s >> 1) & 3);
  const u16* pA0 = A + (long)(row0 + r0s) * lda + ls0 * 8;
  const u16* pA1 = A + (long)(row0 + r1s) * lda + ls1 * 8;
  const u16* pB0 = B + (long)(col0 + r0s) * ldb + ls0 * 8;
  const u16* pB1 = B + (long)(col0 + r1s) * ldb + ls1 * 8;
  int dst0 = wv * 1024, dst1 = wv * 1024 + 512;

  f32x4 acc[4][4] = {};

  auto STAGE = [&](int buf, int t) {
    int k0 = t << 5;
    glds16(pA0 + k0, &lA[buf][dst0]);
    glds16(pA1 + k0, &lA[buf][dst1]);
    glds16(pB0 + k0, &lB[buf][dst0]);
    glds16(pB1 + k0, &lB[buf][dst1]);
  };
  auto COMPUTE = [&](int buf) {
    bf16x8 af[4], bfr[4];
#pragma unroll
    for (int m = 0; m < 4; ++m)
      af[m] = *(const bf16x8*)&lA[buf][(wm * 64 + m * 16 + fr) * 32 + kqs * 8];
#pragma unroll
    for (int n = 0; n < 4; ++n)
      bfr[n] = *(const bf16x8*)&lB[buf][(wn * 64 + n * 16 + fr) * 32 + kqs * 8];
#pragma unroll
    for (int m = 0; m < 4; ++m)
#pragma unroll
      for (int n = 0; n < 4; ++n)
        acc[m][n] = __builtin_amdgcn_mfma_f32_16x16x32_bf16(af[m], bfr[n], acc[m][n], 0, 0, 0);
  };

  int nk = K >> 5, cur = 0;
  STAGE(0, 0);
  __syncthreads();
  for (int t = 0; t < nk; ++t) {
    if (t + 1 < nk) STAGE(cur ^ 1, t + 1);
    COMPUTE(cur);
    __syncthreads();
    cur ^= 1;
  }

  if (EPI == 0) {
    float* Cb = (float*)Cv + ((long)b * gridDim.y + ks) * sC;
#pragma unroll
    for (int m = 0; m < 4; ++m)
#pragma unroll
      for (int n = 0; n < 4; ++n)
#pragma unroll
        for (int r = 0; r < 4; ++r) {
          int gr = row0 + wm * 64 + m * 16 + kq * 4 + r;
          int gc = col0 + wn * 64 + n * 16 + fr;
          Cb[(long)gr * ldc + gc] = acc[m][n][r];
        }
  } else if (EPI == 1) {
    __hip_bfloat16* Cb = (__hip_bfloat16*)Cv + (long)b * sC;
#pragma unroll
    for (int m = 0; m < 4; ++m)
#pragma unroll
      for (int n = 0; n < 4; ++n)
#pragma unroll
        for (int r = 0; r < 4; ++r) {
          int gr = row0 + wm * 64 + m * 16 + kq * 4 + r;
          int gc = col0 + wn * 64 + n * 16 + fr;
          Cb[(long)gr * ldc + gc] = __float2bfloat16(acc[m][n][r]);
        }
  } else if (EPI == 2) {
    float* Cb = (float*)Cv + (long)b * sC;
    const float* ub = e3 + (long)b * e34stride;
    const float* wb = e4 + (long)b * e34stride;
#pragma unroll
    for (int m = 0; m < 4; ++m)
#pragma unroll
      for (int n = 0; n < 4; ++n)
#pragma unroll
        for (int r = 0; r < 4; ++r) {
          int gr = row0 + wm * 64 + m * 16 + kq * 4 + r;
          int gc = col0 + wn * 64 + n * 16 + fr;
          float v = acc[m][n][r] + e1[gr] * ub[gc] + e2[gc] * wb[gr] +
                    4096.0f * e1[gr] * e2[gc];
          Cb[(long)gr * ldc + gc] = v * scale;
        }
  }
}

// reduce 4 f32 split-K partials -> Gbf bf16. grid (64, B), block 256
__global__ __launch_bounds__(256) void reduceG_kernel(
    const float* __restrict__ Gp, u16* __restrict__ G) {
  int b = blockIdx.y;
  int e = blockIdx.x * 1024 + threadIdx.x * 4;
  const float* base = Gp + (long)b * 262144;
  float4 s = *(const float4*)(base + e);
#pragma unroll
  for (int sl = 1; sl < 4; ++sl) {
    float4 v = *(const float4*)(base + sl * 65536 + e);
    s.x += v.x; s.y += v.y; s.z += v.z; s.w += v.w;
  }
  ushort4 o;
  o.x = f2b(s.x); o.y = f2b(s.y); o.z = f2b(s.z); o.w = f2b(s.w);
  *(ushort4*)(G + (long)b * 65536 + e) = o;
}

// ---------------------------------------------------------------------------
// softmax over rows of S -> attn^T bf16 (attnT[d][c] = attn[c][d])
__global__ __launch_bounds__(256) void softmax_kernel(const float* __restrict__ S,
                                                      u16* __restrict__ attnT) {
  int row = blockIdx.x;
  int t = threadIdx.x;
  float v = S[(long)row * C + t];
  __shared__ float red[256];
  red[t] = v; __syncthreads();
  for (int st = 128; st > 0; st >>= 1) {
    if (t < st) red[t] = fmaxf(red[t], red[t + st]);
    __syncthreads();
  }
  float mx = red[0];
  __syncthreads();
  float e = __expf(v - mx);
  red[t] = e; __syncthreads();
  for (int st = 128; st > 0; st >>= 1) {
    if (t < st) red[t] += red[t + st];
    __syncthreads();
  }
  float inv = 1.0f / red[0];
  int b = row >> 8, c = row & 255;
  attnT[(long)b * 65536 + t * 256 + c] = f2b(e * inv);
}

// cbias[b][j] = proj_b[j] + sum_d M[b][j][d]*qkv_b[512+d]
__global__ __launch_bounds__(256) void cbias_kernel(const u16* __restrict__ M,
                                                    const float* __restrict__ qkv_b,
                                                    const float* __restrict__ proj_b,
                                                    float* __restrict__ cb) {
  int b = blockIdx.x, j = threadIdx.x;
  const u16* m = M + (long)b * 65536 + (long)j * 256;
  float s = 0.f;
  for (int d = 0; d < C; ++d) s += b2f(m[d]) * qkv_b[512 + d];
  cb[b * C + j] = proj_b[j] + s;
}

// ---------------------------------------------------------------------------
// Fused conv3x3 implicit-GEMM + attention-output GEMM.
// 256x256 tile (full o-range x 256 tokens), BK=32, 8 waves (2Mx4N),
// 3-buffer LDS pipeline with counted vmcnt (T3/T4) + setprio (T5).
// K = 72 conv steps (9 taps x 256 ch) + 8 attn steps (K=256), single acc:
// the attn tile rows n'=o*16+tn, cols j=cc alias the conv tile's output
// bytes with identical fragment indexing.
__global__ __launch_bounds__(512, 2) void convattn_kernel(
    const u16* __restrict__ xT, const u16* __restrict__ cw,
    const u16* __restrict__ W2, const u16* __restrict__ zbuf,
    const float* __restrict__ conv_b, const float* __restrict__ cb,
    float* __restrict__ out) {
  int b = blockIdx.y;
  int tn = blockIdx.x;            // 0..15
  int col0 = tn * 256;
  const u16* xTb = xT + (long)b * CN;
  const u16* W2b = W2 + (long)b * 65536;

  __shared__ u16 lA[3][8192];     // 3 x 16KB A-tiles [256][32]
  __shared__ u16 lB[3][8192];     // 3 x 16KB B-tiles [256][32]

  int tid = threadIdx.x;
  int lane = tid & 63, w = tid >> 6;    // wave 0..7
  int wr = w >> 2, wc = w & 3;          // 2M x 4N wave grid
  int fr = lane & 15, kq = lane >> 4;
  int kqs = kq ^ ((fr >> 1) & 3);

  // staging: wave w stages rows [w*32, w*32+32) as two 1KB chunks
  int rA0 = w * 32 + (lane >> 2);
  int rA1 = rA0 + 16;
  int slot = (lane & 3) ^ ((lane >> 3) & 3);   // XOR slot swizzle (involution)
  int dA0 = w * 1024, dA1 = dA0 + 512;         // u16 offsets (wave-uniform)

  const u16* awA0 = cw + (long)rA0 * 2304 + slot * 8;
  const u16* awA1 = cw + (long)rA1 * 2304 + slot * 8;
  int t0 = col0 + rA0, t1 = col0 + rA1;
  int h0 = t0 >> 6, w0_ = t0 & 63, h1 = t1 >> 6, w1_ = t1 & 63;
  const u16* pB0 = xTb + (long)t0 * 256 + slot * 8;
  const u16* pB1 = xTb + (long)t1 * 256 + slot * 8;
  const u16* zsrc = zbuf + slot * 8;
  const u16* aq0 = xTb + (long)(rA0 * 16 + tn) * 256 + slot * 8;
  const u16* aq1 = xTb + (long)(rA1 * 16 + tn) * 256 + slot * 8;
  const u16* qb0 = W2b + (long)rA0 * 256 + slot * 8;
  const u16* qb1 = W2b + (long)rA1 * 256 + slot * 8;

  f32x4 acc[8][4] = {};

  u16* A0 = lA[0]; u16* A1 = lA[1]; u16* A2 = lA[2];
  u16* B0 = lB[0]; u16* B1 = lB[1]; u16* B2 = lB[2];

  auto STAGE = [&](u16* bA, u16* bB, int t) {
    if (t < 72) {
      int tap = t >> 3, i0 = (t & 7) << 5;
      int dh = tap / 3 - 1, dw = tap % 3 - 1;
      glds16(awA0 + tap * 256 + i0, bA + dA0);
      glds16(awA1 + tap * 256 + i0, bA + dA1);
      long sh = (long)(dh * 64 + dw) * 256 + i0;
      bool v0 = ((unsigned)(h0 + dh) < 64u) && ((unsigned)(w0_ + dw) < 64u);
      bool v1 = ((unsigned)(h1 + dh) < 64u) && ((unsigned)(w1_ + dw) < 64u);
      glds16(v0 ? pB0 + sh : zsrc, bB + dA0);
      glds16(v1 ? pB1 + sh : zsrc, bB + dA1);
    } else {
      int c0k = (t - 72) << 5;
      glds16(aq0 + c0k, bA + dA0);
      glds16(aq1 + c0k, bA + dA1);
      glds16(qb0 + c0k, bB + dA0);
      glds16(qb1 + c0k, bB + dA1);
    }
  };
  auto COMPUTE = [&](const u16* bA, const u16* bB) {
    bf16x8 af[8], bv[4];
#pragma unroll
    for (int mf = 0; mf < 8; ++mf)
      af[mf] = *(const bf16x8*)(bA + (wr * 128 + mf * 16 + fr) * 32 + kqs * 8);
#pragma unroll
    for (int nf = 0; nf < 4; ++nf)
      bv[nf] = *(const bf16x8*)(bB + (wc * 64 + nf * 16 + fr) * 32 + kqs * 8);
    __builtin_amdgcn_s_setprio(1);
#pragma unroll
    for (int mf = 0; mf < 8; ++mf)
#pragma unroll
      for (int nf = 0; nf < 4; ++nf)
        acc[mf][nf] = __builtin_amdgcn_mfma_f32_16x16x32_bf16(af[mf], bv[nf], acc[mf][nf], 0, 0, 0);
    __builtin_amdgcn_s_setprio(0);
  };

  // prologue: 2 tiles in flight, wait only for tile 0 (4 loads stay in flight)
  STAGE(A0, B0, 0);
  STAGE(A1, B1, 1);
  asm volatile("s_waitcnt vmcnt(4)" ::: "memory");
  __builtin_amdgcn_sched_barrier(0);
  __builtin_amdgcn_s_barrier();
  __builtin_amdgcn_sched_barrier(0);

  for (int t = 0; t < 80; ++t) {
    if (t + 2 < 80) {
      STAGE(A2, B2, t + 2);        // issue-early (T14): hides under COMPUTE
      COMPUTE(A0, B0);
      asm volatile("s_waitcnt vmcnt(4)" ::: "memory");  // drain t+1 only
    } else {
      COMPUTE(A0, B0);
      asm volatile("s_waitcnt vmcnt(0)" ::: "memory");  // tail drain
    }
    __builtin_amdgcn_sched_barrier(0);
    __builtin_amdgcn_s_barrier();
    __builtin_amdgcn_sched_barrier(0);
    u16* tA = A0; A0 = A1; A1 = A2; A2 = tA;
    u16* tB = B0; B0 = B1; B1 = B2; B2 = tB;
  }

  float* ob = out + (long)b * CN;
  const float* cbb = cb + b * C;
#pragma unroll
  for (int mf = 0; mf < 8; ++mf) {
    int go = wr * 128 + mf * 16 + kq * 4;
#pragma unroll
    for (int nf = 0; nf < 4; ++nf) {
      int cc = wc * 64 + nf * 16 + fr;
      float cbv = cbb[cc];
#pragma unroll
      for (int r = 0; r < 4; ++r)
        ob[(long)(go + r) * NTOK + col0 + cc] =
            acc[mf][nf][r] + conv_b[go + r] + cbv;
    }
  }
}

// ---------------------------------------------------------------------------
extern "C" void kernel_launch(void* const* d_in, const int* in_sizes, int n_in,
                              void* d_out, int out_size, void* d_ws, size_t ws_size,
                              hipStream_t stream) {
  const float* x = (const float*)d_in[0];
  const float* qkv_w = (const float*)d_in[1];
  const float* qkv_b = (const float*)d_in[2];
  const float* proj_w = (const float*)d_in[3];
  const float* proj_b = (const float*)d_in[4];
  const float* conv_w = (const float*)d_in[5];
  const float* conv_b = (const float*)d_in[6];
  float* out = (float*)d_out;
  char* ws = (char*)d_ws;

  u16* xbf = (u16*)(ws);                    // 32 MB
  u16* xT = (u16*)(ws + 33554432);          // 32 MB
  u16* Gbf = (u16*)(ws + 67108864);         // 2 MB
  // union region: Gpart (16.7 MB, dead after reduceG) overlaps the small
  // intermediates created afterwards.
  float* Gpart = (float*)(ws + 69206016);
  u16* T1bf = (u16*)(ws + 69206016);
  float* Sf = (float*)(ws + 71303168);
  u16* attnT = (u16*)(ws + 75497472);
  u16* Mbf = (u16*)(ws + 77594624);
  u16* W2bf = (u16*)(ws + 79691776);
  u16* Wq = (u16*)(ws + 85983232);
  u16* Wk = (u16*)(ws + 86114304);
  u16* WvT = (u16*)(ws + 86245376);
  u16* Pw = (u16*)(ws + 86376448);
  u16* cw = (u16*)(ws + 86507520);
  float* rws = (float*)(ws + 87687168);
  float* uws = (float*)(ws + 87703552);
  float* wws = (float*)(ws + 87719936);
  float* cb = (float*)(ws + 87736320);
  u16* zbuf = (u16*)(ws + 87752704);

  prep_w_kernel<<<3328, 256, 0, stream>>>(qkv_w, proj_w, conv_w, Wq, Wk, WvT,
                                          Pw, cw, rws, zbuf);
  prep_x_kernel<<<dim3(128, 8, BATCH), 256, 0, stream>>>(x, xbf, xT, rws);
  bias_uw_kernel<<<BATCH, 512, 0, stream>>>(qkv_w, rws, uws, wws);

  // G = X*X^T per batch, split-K x4 -> f32 partials
  gemm_glds_kernel<0><<<dim3(4, 4, BATCH), 256, 0, stream>>>(
      xbf, xbf, Gpart, 1024, 4096, 4096, 256, 2, CN, CN, 65536,
      0.f, nullptr, nullptr, nullptr, nullptr, 0);
  reduceG_kernel<<<dim3(64, BATCH), 256, 0, stream>>>(Gpart, Gbf);

  // T1 = Wq * G  (G symmetric)
  gemm_glds_kernel<1><<<dim3(4, 1, BATCH), 256, 0, stream>>>(
      Wq, Gbf, T1bf, 256, 256, 256, 256, 2, 0, 65536, 65536,
      0.f, nullptr, nullptr, nullptr, nullptr, 0);
  // S = (T1 * Wk^T + bias terms) * scale
  gemm_glds_kernel<2><<<dim3(4, 1, BATCH), 256, 0, stream>>>(
      T1bf, Wk, Sf, 256, 256, 256, 256, 2, 65536, 0, 65536,
      0.0625f, qkv_b, qkv_b + 256, uws, wws, 256);

  softmax_kernel<<<BATCH * C, 256, 0, stream>>>(Sf, attnT);

  // M = Pw * attn   (B operand = attn^T)
  gemm_glds_kernel<1><<<dim3(4, 1, BATCH), 256, 0, stream>>>(
      Pw, attnT, Mbf, 256, 256, 256, 256, 2, 0, 65536, 65536,
      0.f, nullptr, nullptr, nullptr, nullptr, 0);
  cbias_kernel<<<BATCH, 256, 0, stream>>>(Mbf, qkv_b, proj_b, cb);
  // W2 = M * Wv     (B operand = WvT)
  gemm_glds_kernel<1><<<dim3(4, 1, BATCH), 256, 0, stream>>>(
      Mbf, WvT, W2bf, 256, 256, 256, 256, 2, 65536, 0, 65536,
      0.f, nullptr, nullptr, nullptr, nullptr, 0);

  // fused conv + attention-output, single store of out
  convattn_kernel<<<dim3(16, BATCH), 512, 0, stream>>>(xT, cw, W2bf, zbuf,
                                                       conv_b, cb, out);
}

// Round 4
// 581.644 us; speedup vs baseline: 1.0007x; 1.0007x over previous
//
#include <hip/hip_runtime.h>
#include <hip/hip_bf16.h>

typedef unsigned short u16;
typedef __bf16 bf16x8 __attribute__((ext_vector_type(8)));
typedef float f32x4 __attribute__((ext_vector_type(4)));

#define BATCH 16
#define C 256
#define NTOK 4096      // H*W
#define CN 1048576     // C*NTOK

__device__ __forceinline__ u16 f2b(float f) {
  __hip_bfloat16 h = __float2bfloat16(f);
  return __builtin_bit_cast(u16, h);
}
__device__ __forceinline__ float b2f(u16 u) {
  unsigned int x = ((unsigned int)u) << 16;
  return __builtin_bit_cast(float, x);
}

// async global->LDS, 16B per lane. LDS dest must be wave-uniform base
// (HW adds lane*16); global src is per-lane.
__device__ __forceinline__ void glds16(const u16* g, u16* l) {
  __builtin_amdgcn_global_load_lds(
      (const __attribute__((address_space(1))) unsigned int*)(g),
      (__attribute__((address_space(3))) unsigned int*)(l), 16, 0, 0);
}

// ---------------------------------------------------------------------------
// prep_x: x f32 [B][C][N] -> xbf [B][C][N], xT [B][N][C]; row partial sums
// atomically into rws (rws zeroed by prep_w, launched before).
// grid (128, 8, B), block 256
__global__ __launch_bounds__(256) void prep_x_kernel(
    const float* __restrict__ x, u16* __restrict__ xbf, u16* __restrict__ xT,
    float* __restrict__ rws) {
  __shared__ float t[32][33];
  int b = blockIdx.z;
  int c0 = blockIdx.y * 32, n0 = blockIdx.x * 32;
  int tid = threadIdx.x;
  int i = tid >> 3, j4 = (tid & 7) * 4;
  const float* xb = x + (long)b * CN;
  float4 v = *(const float4*)(xb + (long)(c0 + i) * NTOK + n0 + j4);
  ushort4 bv;
  bv.x = f2b(v.x); bv.y = f2b(v.y); bv.z = f2b(v.z); bv.w = f2b(v.w);
  *(ushort4*)(xbf + (long)b * CN + (long)(c0 + i) * NTOK + n0 + j4) = bv;
  t[i][j4 + 0] = v.x; t[i][j4 + 1] = v.y; t[i][j4 + 2] = v.z; t[i][j4 + 3] = v.w;
  __syncthreads();
  ushort4 o;
  o.x = f2b(t[j4 + 0][i]); o.y = f2b(t[j4 + 1][i]);
  o.z = f2b(t[j4 + 2][i]); o.w = f2b(t[j4 + 3][i]);
  *(ushort4*)(xT + (long)b * CN + (long)(n0 + i) * C + c0 + j4) = o;
  if (tid < 32) {
    float s = 0.f;
#pragma unroll
    for (int j = 0; j < 32; ++j) s += t[tid][j];
    atomicAdd(&rws[b * C + c0 + tid], s);
  }
}

// ---------------------------------------------------------------------------
// prep_w: bf16-convert weights; WvT transposed; conv w reordered [o][tap][i];
// also zeroes rws and zbuf. grid 3328 x 256.
__global__ __launch_bounds__(256) void prep_w_kernel(
    const float* __restrict__ qkv_w, const float* __restrict__ proj_w,
    const float* __restrict__ conv_w, u16* __restrict__ Wq, u16* __restrict__ Wk,
    u16* __restrict__ WvT, u16* __restrict__ Pw, u16* __restrict__ cw,
    float* __restrict__ rws, u16* __restrict__ zbuf) {
  int idx = blockIdx.x * 256 + threadIdx.x;
  if (idx < 4096) rws[idx] = 0.f;
  if (idx < 256) zbuf[idx] = 0;
  if (idx < 65536) {
    Wq[idx] = f2b(qkv_w[idx]);
  } else if (idx < 131072) {
    int e = idx - 65536;
    Wk[e] = f2b(qkv_w[65536 + e]);
  } else if (idx < 196608) {
    int e = idx - 131072;
    int i = e >> 8, d = e & 255;
    WvT[e] = f2b(qkv_w[131072 + d * 256 + i]);
  } else if (idx < 262144) {
    int e = idx - 196608;
    Pw[e] = f2b(proj_w[e]);
  } else if (idx < 851968) {
    int e = idx - 262144;
    int o = e / 2304;
    int rem = e - o * 2304;
    int tap = rem >> 8, i = rem & 255;
    cw[e] = f2b(conv_w[o * 2304 + i * 9 + tap]);
  }
}

// bias_uw: u[b][d] = Wk[d,:]*r[b,:] ; w[b][c] = Wq[c,:]*r[b,:]
__global__ __launch_bounds__(512) void bias_uw_kernel(
    const float* __restrict__ qkv_w, const float* __restrict__ r,
    float* __restrict__ u, float* __restrict__ w) {
  int b = blockIdx.x, t = threadIdx.x;
  const float* rb = r + b * C;
  if (t < 256) {
    float s = 0.f;
    for (int i = 0; i < C; ++i) s += qkv_w[(256 + t) * 256 + i] * rb[i];
    u[b * C + t] = s;
  } else {
    int c = t - 256;
    float s = 0.f;
    for (int i = 0; i < C; ++i) s += qkv_w[c * 256 + i] * rb[i];
    w[b * C + c] = s;
  }
}

// ---------------------------------------------------------------------------
// Generic GEMM C = A*B^T (both K-contiguous), 128x128 tile, BK=32, 4 waves,
// global_load_lds staging + slot-XOR swizzle, double-buffered.
// grid (tilesM*tilesN, ksplit, batch)
// EPI 0: f32 partial store at (b*gridDim.y+ks)*sC. EPI 1: bf16. EPI 2: S-epi.
template <int EPI>
__global__ __launch_bounds__(256, 2) void gemm_glds_kernel(
    const u16* __restrict__ A, const u16* __restrict__ B, void* __restrict__ Cv,
    int K, int lda, int ldb, int ldc, int tilesN, long sA, long sB, long sC,
    float scale, const float* __restrict__ e1, const float* __restrict__ e2,
    const float* __restrict__ e3, const float* __restrict__ e4, int e34stride) {
  int b = blockIdx.z, ks = blockIdx.y;
  A += (long)b * sA + (long)ks * K;
  B += (long)b * sB + (long)ks * K;
  int ty = blockIdx.x / tilesN, tx = blockIdx.x % tilesN;
  int row0 = ty * 128, col0 = tx * 128;

  __shared__ u16 lA[2][4096];
  __shared__ u16 lB[2][4096];

  int tid = threadIdx.x;
  int lane = tid & 63, wv = tid >> 6;
  int wm = wv >> 1, wn = wv & 1;
  int fr = lane & 15, kq = lane >> 4;
  int kqs = kq ^ ((fr >> 1) & 3);

  // staging chunks: c0 = wv*128+lane, c1 = c0+64 (16B each)
  int c0 = wv * 128 + lane, c1 = c0 + 64;
  int r0s = c0 >> 2, r1s = c1 >> 2;
  int ls0 = (c0 & 3) ^ ((r0s >> 1) & 3);
  int ls1 = (c1 & 3) ^ ((r1s >> 1) & 3);
  const u16* pA0 = A + (long)(row0 + r0s) * lda + ls0 * 8;
  const u16* pA1 = A + (long)(row0 + r1s) * lda + ls1 * 8;
  const u16* pB0 = B + (long)(col0 + r0s) * ldb + ls0 * 8;
  const u16* pB1 = B + (long)(col0 + r1s) * ldb + ls1 * 8;
  int dst0 = wv * 1024, dst1 = wv * 1024 + 512;

  f32x4 acc[4][4] = {};

  auto STAGE = [&](int buf, int t) {
    int k0 = t << 5;
    glds16(pA0 + k0, &lA[buf][dst0]);
    glds16(pA1 + k0, &lA[buf][dst1]);
    glds16(pB0 + k0, &lB[buf][dst0]);
    glds16(pB1 + k0, &lB[buf][dst1]);
  };
  auto COMPUTE = [&](int buf) {
    bf16x8 af[4], bfr[4];
#pragma unroll
    for (int m = 0; m < 4; ++m)
      af[m] = *(const bf16x8*)&lA[buf][(wm * 64 + m * 16 + fr) * 32 + kqs * 8];
#pragma unroll
    for (int n = 0; n < 4; ++n)
      bfr[n] = *(const bf16x8*)&lB[buf][(wn * 64 + n * 16 + fr) * 32 + kqs * 8];
#pragma unroll
    for (int m = 0; m < 4; ++m)
#pragma unroll
      for (int n = 0; n < 4; ++n)
        acc[m][n] = __builtin_amdgcn_mfma_f32_16x16x32_bf16(af[m], bfr[n], acc[m][n], 0, 0, 0);
  };

  int nk = K >> 5, cur = 0;
  STAGE(0, 0);
  __syncthreads();
  for (int t = 0; t < nk; ++t) {
    if (t + 1 < nk) STAGE(cur ^ 1, t + 1);
    COMPUTE(cur);
    __syncthreads();
    cur ^= 1;
  }

  if (EPI == 0) {
    float* Cb = (float*)Cv + ((long)b * gridDim.y + ks) * sC;
#pragma unroll
    for (int m = 0; m < 4; ++m)
#pragma unroll
      for (int n = 0; n < 4; ++n)
#pragma unroll
        for (int r = 0; r < 4; ++r) {
          int gr = row0 + wm * 64 + m * 16 + kq * 4 + r;
          int gc = col0 + wn * 64 + n * 16 + fr;
          Cb[(long)gr * ldc + gc] = acc[m][n][r];
        }
  } else if (EPI == 1) {
    __hip_bfloat16* Cb = (__hip_bfloat16*)Cv + (long)b * sC;
#pragma unroll
    for (int m = 0; m < 4; ++m)
#pragma unroll
      for (int n = 0; n < 4; ++n)
#pragma unroll
        for (int r = 0; r < 4; ++r) {
          int gr = row0 + wm * 64 + m * 16 + kq * 4 + r;
          int gc = col0 + wn * 64 + n * 16 + fr;
          Cb[(long)gr * ldc + gc] = __float2bfloat16(acc[m][n][r]);
        }
  } else if (EPI == 2) {
    float* Cb = (float*)Cv + (long)b * sC;
    const float* ub = e3 + (long)b * e34stride;
    const float* wb = e4 + (long)b * e34stride;
#pragma unroll
    for (int m = 0; m < 4; ++m)
#pragma unroll
      for (int n = 0; n < 4; ++n)
#pragma unroll
        for (int r = 0; r < 4; ++r) {
          int gr = row0 + wm * 64 + m * 16 + kq * 4 + r;
          int gc = col0 + wn * 64 + n * 16 + fr;
          float v = acc[m][n][r] + e1[gr] * ub[gc] + e2[gc] * wb[gr] +
                    4096.0f * e1[gr] * e2[gc];
          Cb[(long)gr * ldc + gc] = v * scale;
        }
  }
}

// reduce 4 f32 split-K partials -> Gbf bf16. grid (64, B), block 256
__global__ __launch_bounds__(256) void reduceG_kernel(
    const float* __restrict__ Gp, u16* __restrict__ G) {
  int b = blockIdx.y;
  int e = blockIdx.x * 1024 + threadIdx.x * 4;
  const float* base = Gp + (long)b * 262144;
  float4 s = *(const float4*)(base + e);
#pragma unroll
  for (int sl = 1; sl < 4; ++sl) {
    float4 v = *(const float4*)(base + sl * 65536 + e);
    s.x += v.x; s.y += v.y; s.z += v.z; s.w += v.w;
  }
  ushort4 o;
  o.x = f2b(s.x); o.y = f2b(s.y); o.z = f2b(s.z); o.w = f2b(s.w);
  *(ushort4*)(G + (long)b * 65536 + e) = o;
}

// ---------------------------------------------------------------------------
// softmax over rows of S -> attn^T bf16 (attnT[d][c] = attn[c][d])
__global__ __launch_bounds__(256) void softmax_kernel(const float* __restrict__ S,
                                                      u16* __restrict__ attnT) {
  int row = blockIdx.x;
  int t = threadIdx.x;
  float v = S[(long)row * C + t];
  __shared__ float red[256];
  red[t] = v; __syncthreads();
  for (int st = 128; st > 0; st >>= 1) {
    if (t < st) red[t] = fmaxf(red[t], red[t + st]);
    __syncthreads();
  }
  float mx = red[0];
  __syncthreads();
  float e = __expf(v - mx);
  red[t] = e; __syncthreads();
  for (int st = 128; st > 0; st >>= 1) {
    if (t < st) red[t] += red[t + st];
    __syncthreads();
  }
  float inv = 1.0f / red[0];
  int b = row >> 8, c = row & 255;
  attnT[(long)b * 65536 + t * 256 + c] = f2b(e * inv);
}

// cbias[b][j] = proj_b[j] + sum_d M[b][j][d]*qkv_b[512+d]
__global__ __launch_bounds__(256) void cbias_kernel(const u16* __restrict__ M,
                                                    const float* __restrict__ qkv_b,
                                                    const float* __restrict__ proj_b,
                                                    float* __restrict__ cb) {
  int b = blockIdx.x, j = threadIdx.x;
  const u16* m = M + (long)b * 65536 + (long)j * 256;
  float s = 0.f;
  for (int d = 0; d < C; ++d) s += b2f(m[d]) * qkv_b[512 + d];
  cb[b * C + j] = proj_b[j] + s;
}

// ---------------------------------------------------------------------------
// Fused conv3x3 implicit-GEMM + attention-output GEMM.
// 256x256 tile (full o-range x 256 tokens), BK=32, 8 waves (2Mx4N),
// 3-buffer LDS pipeline with counted vmcnt (T3/T4) + setprio (T5).
// K = 72 conv steps (9 taps x 256 ch) + 8 attn steps (K=256), single acc.
// __launch_bounds__(512, 1): 1 wave/SIMD floor -> VGPR cap 512. Round-3's
// (512,2) capped VGPRs at 128 = exactly acc[8][4], spilling af/bv/addresses
// to scratch (944 MB WRITE_SIZE). LDS (96KB) limits to 1 block/CU anyway.
__global__ __launch_bounds__(512, 1) void convattn_kernel(
    const u16* __restrict__ xT, const u16* __restrict__ cw,
    const u16* __restrict__ W2, const u16* __restrict__ zbuf,
    const float* __restrict__ conv_b, const float* __restrict__ cb,
    float* __restrict__ out) {
  int b = blockIdx.y;
  int tn = blockIdx.x;            // 0..15
  int col0 = tn * 256;
  const u16* xTb = xT + (long)b * CN;
  const u16* W2b = W2 + (long)b * 65536;

  __shared__ u16 lA[3][8192];     // 3 x 16KB A-tiles [256][32]
  __shared__ u16 lB[3][8192];     // 3 x 16KB B-tiles [256][32]

  int tid = threadIdx.x;
  int lane = tid & 63, w = tid >> 6;    // wave 0..7
  int wr = w >> 2, wc = w & 3;          // 2M x 4N wave grid
  int fr = lane & 15, kq = lane >> 4;
  int kqs = kq ^ ((fr >> 1) & 3);

  // staging: wave w stages rows [w*32, w*32+32) as two 1KB chunks
  int rA0 = w * 32 + (lane >> 2);
  int rA1 = rA0 + 16;
  int slot = (lane & 3) ^ ((lane >> 3) & 3);   // XOR slot swizzle (involution)
  int dA0 = w * 1024, dA1 = dA0 + 512;         // u16 offsets (wave-uniform)

  const u16* awA0 = cw + (long)rA0 * 2304 + slot * 8;
  const u16* awA1 = cw + (long)rA1 * 2304 + slot * 8;
  int t0 = col0 + rA0, t1 = col0 + rA1;
  int h0 = t0 >> 6, w0_ = t0 & 63, h1 = t1 >> 6, w1_ = t1 & 63;
  const u16* pB0 = xTb + (long)t0 * 256 + slot * 8;
  const u16* pB1 = xTb + (long)t1 * 256 + slot * 8;
  const u16* zsrc = zbuf + slot * 8;
  const u16* aq0 = xTb + (long)(rA0 * 16 + tn) * 256 + slot * 8;
  const u16* aq1 = xTb + (long)(rA1 * 16 + tn) * 256 + slot * 8;
  const u16* qb0 = W2b + (long)rA0 * 256 + slot * 8;
  const u16* qb1 = W2b + (long)rA1 * 256 + slot * 8;

  f32x4 acc[8][4] = {};

  u16* A0 = lA[0]; u16* A1 = lA[1]; u16* A2 = lA[2];
  u16* B0 = lB[0]; u16* B1 = lB[1]; u16* B2 = lB[2];

  auto STAGE = [&](u16* bA, u16* bB, int t) {
    if (t < 72) {
      int tap = t >> 3, i0 = (t & 7) << 5;
      int dh = tap / 3 - 1, dw = tap % 3 - 1;
      glds16(awA0 + tap * 256 + i0, bA + dA0);
      glds16(awA1 + tap * 256 + i0, bA + dA1);
      long sh = (long)(dh * 64 + dw) * 256 + i0;
      bool v0 = ((unsigned)(h0 + dh) < 64u) && ((unsigned)(w0_ + dw) < 64u);
      bool v1 = ((unsigned)(h1 + dh) < 64u) && ((unsigned)(w1_ + dw) < 64u);
      glds16(v0 ? pB0 + sh : zsrc, bB + dA0);
      glds16(v1 ? pB1 + sh : zsrc, bB + dA1);
    } else {
      int c0k = (t - 72) << 5;
      glds16(aq0 + c0k, bA + dA0);
      glds16(aq1 + c0k, bA + dA1);
      glds16(qb0 + c0k, bB + dA0);
      glds16(qb1 + c0k, bB + dA1);
    }
  };
  auto COMPUTE = [&](const u16* bA, const u16* bB) {
    bf16x8 af[8], bv[4];
#pragma unroll
    for (int mf = 0; mf < 8; ++mf)
      af[mf] = *(const bf16x8*)(bA + (wr * 128 + mf * 16 + fr) * 32 + kqs * 8);
#pragma unroll
    for (int nf = 0; nf < 4; ++nf)
      bv[nf] = *(const bf16x8*)(bB + (wc * 64 + nf * 16 + fr) * 32 + kqs * 8);
    __builtin_amdgcn_s_setprio(1);
#pragma unroll
    for (int mf = 0; mf < 8; ++mf)
#pragma unroll
      for (int nf = 0; nf < 4; ++nf)
        acc[mf][nf] = __builtin_amdgcn_mfma_f32_16x16x32_bf16(af[mf], bv[nf], acc[mf][nf], 0, 0, 0);
    __builtin_amdgcn_s_setprio(0);
  };

  // prologue: 2 tiles in flight, wait only for tile 0 (4 loads stay in flight)
  STAGE(A0, B0, 0);
  STAGE(A1, B1, 1);
  asm volatile("s_waitcnt vmcnt(4)" ::: "memory");
  __builtin_amdgcn_sched_barrier(0);
  __builtin_amdgcn_s_barrier();
  __builtin_amdgcn_sched_barrier(0);

  for (int t = 0; t < 80; ++t) {
    if (t + 2 < 80) {
      STAGE(A2, B2, t + 2);        // issue-early (T14): hides under COMPUTE
      COMPUTE(A0, B0);
      asm volatile("s_waitcnt vmcnt(4)" ::: "memory");  // drain t+1 only
    } else {
      COMPUTE(A0, B0);
      asm volatile("s_waitcnt vmcnt(0)" ::: "memory");  // tail drain
    }
    __builtin_amdgcn_sched_barrier(0);
    __builtin_amdgcn_s_barrier();
    __builtin_amdgcn_sched_barrier(0);
    u16* tA = A0; A0 = A1; A1 = A2; A2 = tA;
    u16* tB = B0; B0 = B1; B1 = B2; B2 = tB;
  }

  float* ob = out + (long)b * CN;
  const float* cbb = cb + b * C;
#pragma unroll
  for (int mf = 0; mf < 8; ++mf) {
    int go = wr * 128 + mf * 16 + kq * 4;
#pragma unroll
    for (int nf = 0; nf < 4; ++nf) {
      int cc = wc * 64 + nf * 16 + fr;
      float cbv = cbb[cc];
#pragma unroll
      for (int r = 0; r < 4; ++r)
        ob[(long)(go + r) * NTOK + col0 + cc] =
            acc[mf][nf][r] + conv_b[go + r] + cbv;
    }
  }
}

// ---------------------------------------------------------------------------
extern "C" void kernel_launch(void* const* d_in, const int* in_sizes, int n_in,
                              void* d_out, int out_size, void* d_ws, size_t ws_size,
                              hipStream_t stream) {
  const float* x = (const float*)d_in[0];
  const float* qkv_w = (const float*)d_in[1];
  const float* qkv_b = (const float*)d_in[2];
  const float* proj_w = (const float*)d_in[3];
  const float* proj_b = (const float*)d_in[4];
  const float* conv_w = (const float*)d_in[5];
  const float* conv_b = (const float*)d_in[6];
  float* out = (float*)d_out;
  char* ws = (char*)d_ws;

  u16* xbf = (u16*)(ws);                    // 32 MB
  u16* xT = (u16*)(ws + 33554432);          // 32 MB
  u16* Gbf = (u16*)(ws + 67108864);         // 2 MB
  // union region: Gpart (16.7 MB, dead after reduceG) overlaps the small
  // intermediates created afterwards.
  float* Gpart = (float*)(ws + 69206016);
  u16* T1bf = (u16*)(ws + 69206016);
  float* Sf = (float*)(ws + 71303168);
  u16* attnT = (u16*)(ws + 75497472);
  u16* Mbf = (u16*)(ws + 77594624);
  u16* W2bf = (u16*)(ws + 79691776);
  u16* Wq = (u16*)(ws + 85983232);
  u16* Wk = (u16*)(ws + 86114304);
  u16* WvT = (u16*)(ws + 86245376);
  u16* Pw = (u16*)(ws + 86376448);
  u16* cw = (u16*)(ws + 86507520);
  float* rws = (float*)(ws + 87687168);
  float* uws = (float*)(ws + 87703552);
  float* wws = (float*)(ws + 87719936);
  float* cb = (float*)(ws + 87736320);
  u16* zbuf = (u16*)(ws + 87752704);

  prep_w_kernel<<<3328, 256, 0, stream>>>(qkv_w, proj_w, conv_w, Wq, Wk, WvT,
                                          Pw, cw, rws, zbuf);
  prep_x_kernel<<<dim3(128, 8, BATCH), 256, 0, stream>>>(x, xbf, xT, rws);
  bias_uw_kernel<<<BATCH, 512, 0, stream>>>(qkv_w, rws, uws, wws);

  // G = X*X^T per batch, split-K x4 -> f32 partials
  gemm_glds_kernel<0><<<dim3(4, 4, BATCH), 256, 0, stream>>>(
      xbf, xbf, Gpart, 1024, 4096, 4096, 256, 2, CN, CN, 65536,
      0.f, nullptr, nullptr, nullptr, nullptr, 0);
  reduceG_kernel<<<dim3(64, BATCH), 256, 0, stream>>>(Gpart, Gbf);

  // T1 = Wq * G  (G symmetric)
  gemm_glds_kernel<1><<<dim3(4, 1, BATCH), 256, 0, stream>>>(
      Wq, Gbf, T1bf, 256, 256, 256, 256, 2, 0, 65536, 65536,
      0.f, nullptr, nullptr, nullptr, nullptr, 0);
  // S = (T1 * Wk^T + bias terms) * scale
  gemm_glds_kernel<2><<<dim3(4, 1, BATCH), 256, 0, stream>>>(
      T1bf, Wk, Sf, 256, 256, 256, 256, 2, 65536, 0, 65536,
      0.0625f, qkv_b, qkv_b + 256, uws, wws, 256);

  softmax_kernel<<<BATCH * C, 256, 0, stream>>>(Sf, attnT);

  // M = Pw * attn   (B operand = attn^T)
  gemm_glds_kernel<1><<<dim3(4, 1, BATCH), 256, 0, stream>>>(
      Pw, attnT, Mbf, 256, 256, 256, 256, 2, 0, 65536, 65536,
      0.f, nullptr, nullptr, nullptr, nullptr, 0);
  cbias_kernel<<<BATCH, 256, 0, stream>>>(Mbf, qkv_b, proj_b, cb);
  // W2 = M * Wv     (B operand = WvT)
  gemm_glds_kernel<1><<<dim3(4, 1, BATCH), 256, 0, stream>>>(
      Mbf, WvT, W2bf, 256, 256, 256, 256, 2, 65536, 0, 65536,
      0.f, nullptr, nullptr, nullptr, nullptr, 0);

  // fused conv + attention-output, single store of out
  convattn_kernel<<<dim3(16, BATCH), 512, 0, stream>>>(xT, cw, W2bf, zbuf,
                                                       conv_b, cb, out);
}

// Round 5
// 260.479 us; speedup vs baseline: 2.2345x; 2.2330x over previous
//
#include <hip/hip_runtime.h>
#include <hip/hip_bf16.h>

typedef unsigned short u16;
typedef __bf16 bf16x8 __attribute__((ext_vector_type(8)));
typedef float f32x4 __attribute__((ext_vector_type(4)));

#define BATCH 16
#define C 256
#define NTOK 4096      // H*W
#define CN 1048576     // C*NTOK

__device__ __forceinline__ u16 f2b(float f) {
  __hip_bfloat16 h = __float2bfloat16(f);
  return __builtin_bit_cast(u16, h);
}
__device__ __forceinline__ float b2f(u16 u) {
  unsigned int x = ((unsigned int)u) << 16;
  return __builtin_bit_cast(float, x);
}

// async global->LDS, 16B per lane. LDS dest must be wave-uniform base
// (HW adds lane*16); global src is per-lane.
__device__ __forceinline__ void glds16(const u16* g, u16* l) {
  __builtin_amdgcn_global_load_lds(
      (const __attribute__((address_space(1))) unsigned int*)(g),
      (__attribute__((address_space(3))) unsigned int*)(l), 16, 0, 0);
}

// ---------------------------------------------------------------------------
// prep_x: x f32 [B][C][N] -> xbf [B][C][N], xT [B][N][C]; row partial sums
// atomically into rws (rws zeroed by prep_w, launched before).
// grid (128, 8, B), block 256
__global__ __launch_bounds__(256) void prep_x_kernel(
    const float* __restrict__ x, u16* __restrict__ xbf, u16* __restrict__ xT,
    float* __restrict__ rws) {
  __shared__ float t[32][33];
  int b = blockIdx.z;
  int c0 = blockIdx.y * 32, n0 = blockIdx.x * 32;
  int tid = threadIdx.x;
  int i = tid >> 3, j4 = (tid & 7) * 4;
  const float* xb = x + (long)b * CN;
  float4 v = *(const float4*)(xb + (long)(c0 + i) * NTOK + n0 + j4);
  ushort4 bv;
  bv.x = f2b(v.x); bv.y = f2b(v.y); bv.z = f2b(v.z); bv.w = f2b(v.w);
  *(ushort4*)(xbf + (long)b * CN + (long)(c0 + i) * NTOK + n0 + j4) = bv;
  t[i][j4 + 0] = v.x; t[i][j4 + 1] = v.y; t[i][j4 + 2] = v.z; t[i][j4 + 3] = v.w;
  __syncthreads();
  ushort4 o;
  o.x = f2b(t[j4 + 0][i]); o.y = f2b(t[j4 + 1][i]);
  o.z = f2b(t[j4 + 2][i]); o.w = f2b(t[j4 + 3][i]);
  *(ushort4*)(xT + (long)b * CN + (long)(n0 + i) * C + c0 + j4) = o;
  if (tid < 32) {
    float s = 0.f;
#pragma unroll
    for (int j = 0; j < 32; ++j) s += t[tid][j];
    atomicAdd(&rws[b * C + c0 + tid], s);
  }
}

// ---------------------------------------------------------------------------
// prep_w: bf16-convert weights; WvT transposed; conv w reordered [o][tap][i];
// also zeroes rws and zbuf. grid 3328 x 256.
__global__ __launch_bounds__(256) void prep_w_kernel(
    const float* __restrict__ qkv_w, const float* __restrict__ proj_w,
    const float* __restrict__ conv_w, u16* __restrict__ Wq, u16* __restrict__ Wk,
    u16* __restrict__ WvT, u16* __restrict__ Pw, u16* __restrict__ cw,
    float* __restrict__ rws, u16* __restrict__ zbuf) {
  int idx = blockIdx.x * 256 + threadIdx.x;
  if (idx < 4096) rws[idx] = 0.f;
  if (idx < 256) zbuf[idx] = 0;
  if (idx < 65536) {
    Wq[idx] = f2b(qkv_w[idx]);
  } else if (idx < 131072) {
    int e = idx - 65536;
    Wk[e] = f2b(qkv_w[65536 + e]);
  } else if (idx < 196608) {
    int e = idx - 131072;
    int i = e >> 8, d = e & 255;
    WvT[e] = f2b(qkv_w[131072 + d * 256 + i]);
  } else if (idx < 262144) {
    int e = idx - 196608;
    Pw[e] = f2b(proj_w[e]);
  } else if (idx < 851968) {
    int e = idx - 262144;
    int o = e / 2304;
    int rem = e - o * 2304;
    int tap = rem >> 8, i = rem & 255;
    cw[e] = f2b(conv_w[o * 2304 + i * 9 + tap]);
  }
}

// bias_uw: u[b][d] = Wk[d,:]*r[b,:] ; w[b][c] = Wq[c,:]*r[b,:]
__global__ __launch_bounds__(512) void bias_uw_kernel(
    const float* __restrict__ qkv_w, const float* __restrict__ r,
    float* __restrict__ u, float* __restrict__ w) {
  int b = blockIdx.x, t = threadIdx.x;
  const float* rb = r + b * C;
  if (t < 256) {
    float s = 0.f;
    for (int i = 0; i < C; ++i) s += qkv_w[(256 + t) * 256 + i] * rb[i];
    u[b * C + t] = s;
  } else {
    int c = t - 256;
    float s = 0.f;
    for (int i = 0; i < C; ++i) s += qkv_w[c * 256 + i] * rb[i];
    w[b * C + c] = s;
  }
}

// ---------------------------------------------------------------------------
// Generic GEMM C = A*B^T (both K-contiguous), 128x128 tile, BK=32, 4 waves,
// global_load_lds staging + slot-XOR swizzle, double-buffered.
// grid (tilesM*tilesN, ksplit, batch)
// EPI 0: f32 partial store at (b*gridDim.y+ks)*sC. EPI 1: bf16. EPI 2: S-epi.
template <int EPI>
__global__ __launch_bounds__(256, 2) void gemm_glds_kernel(
    const u16* __restrict__ A, const u16* __restrict__ B, void* __restrict__ Cv,
    int K, int lda, int ldb, int ldc, int tilesN, long sA, long sB, long sC,
    float scale, const float* __restrict__ e1, const float* __restrict__ e2,
    const float* __restrict__ e3, const float* __restrict__ e4, int e34stride) {
  int b = blockIdx.z, ks = blockIdx.y;
  A += (long)b * sA + (long)ks * K;
  B += (long)b * sB + (long)ks * K;
  int ty = blockIdx.x / tilesN, tx = blockIdx.x % tilesN;
  int row0 = ty * 128, col0 = tx * 128;

  __shared__ u16 lA[2][4096];
  __shared__ u16 lB[2][4096];

  int tid = threadIdx.x;
  int lane = tid & 63, wv = tid >> 6;
  int wm = wv >> 1, wn = wv & 1;
  int fr = lane & 15, kq = lane >> 4;
  int kqs = kq ^ ((fr >> 1) & 3);

  // staging chunks: c0 = wv*128+lane, c1 = c0+64 (16B each)
  int c0 = wv * 128 + lane, c1 = c0 + 64;
  int r0s = c0 >> 2, r1s = c1 >> 2;
  int ls0 = (c0 & 3) ^ ((r0s >> 1) & 3);
  int ls1 = (c1 & 3) ^ ((r1s >> 1) & 3);
  const u16* pA0 = A + (long)(row0 + r0s) * lda + ls0 * 8;
  const u16* pA1 = A + (long)(row0 + r1s) * lda + ls1 * 8;
  const u16* pB0 = B + (long)(col0 + r0s) * ldb + ls0 * 8;
  const u16* pB1 = B + (long)(col0 + r1s) * ldb + ls1 * 8;
  int dst0 = wv * 1024, dst1 = wv * 1024 + 512;

  f32x4 acc[4][4] = {};

  auto STAGE = [&](int buf, int t) {
    int k0 = t << 5;
    glds16(pA0 + k0, &lA[buf][dst0]);
    glds16(pA1 + k0, &lA[buf][dst1]);
    glds16(pB0 + k0, &lB[buf][dst0]);
    glds16(pB1 + k0, &lB[buf][dst1]);
  };
  auto COMPUTE = [&](int buf) {
    bf16x8 af[4], bfr[4];
#pragma unroll
    for (int m = 0; m < 4; ++m)
      af[m] = *(const bf16x8*)&lA[buf][(wm * 64 + m * 16 + fr) * 32 + kqs * 8];
#pragma unroll
    for (int n = 0; n < 4; ++n)
      bfr[n] = *(const bf16x8*)&lB[buf][(wn * 64 + n * 16 + fr) * 32 + kqs * 8];
#pragma unroll
    for (int m = 0; m < 4; ++m)
#pragma unroll
      for (int n = 0; n < 4; ++n)
        acc[m][n] = __builtin_amdgcn_mfma_f32_16x16x32_bf16(af[m], bfr[n], acc[m][n], 0, 0, 0);
  };

  int nk = K >> 5, cur = 0;
  STAGE(0, 0);
  __syncthreads();
  for (int t = 0; t < nk; ++t) {
    if (t + 1 < nk) STAGE(cur ^ 1, t + 1);
    COMPUTE(cur);
    __syncthreads();
    cur ^= 1;
  }

  if (EPI == 0) {
    float* Cb = (float*)Cv + ((long)b * gridDim.y + ks) * sC;
#pragma unroll
    for (int m = 0; m < 4; ++m)
#pragma unroll
      for (int n = 0; n < 4; ++n)
#pragma unroll
        for (int r = 0; r < 4; ++r) {
          int gr = row0 + wm * 64 + m * 16 + kq * 4 + r;
          int gc = col0 + wn * 64 + n * 16 + fr;
          Cb[(long)gr * ldc + gc] = acc[m][n][r];
        }
  } else if (EPI == 1) {
    __hip_bfloat16* Cb = (__hip_bfloat16*)Cv + (long)b * sC;
#pragma unroll
    for (int m = 0; m < 4; ++m)
#pragma unroll
      for (int n = 0; n < 4; ++n)
#pragma unroll
        for (int r = 0; r < 4; ++r) {
          int gr = row0 + wm * 64 + m * 16 + kq * 4 + r;
          int gc = col0 + wn * 64 + n * 16 + fr;
          Cb[(long)gr * ldc + gc] = __float2bfloat16(acc[m][n][r]);
        }
  } else if (EPI == 2) {
    float* Cb = (float*)Cv + (long)b * sC;
    const float* ub = e3 + (long)b * e34stride;
    const float* wb = e4 + (long)b * e34stride;
#pragma unroll
    for (int m = 0; m < 4; ++m)
#pragma unroll
      for (int n = 0; n < 4; ++n)
#pragma unroll
        for (int r = 0; r < 4; ++r) {
          int gr = row0 + wm * 64 + m * 16 + kq * 4 + r;
          int gc = col0 + wn * 64 + n * 16 + fr;
          float v = acc[m][n][r] + e1[gr] * ub[gc] + e2[gc] * wb[gr] +
                    4096.0f * e1[gr] * e2[gc];
          Cb[(long)gr * ldc + gc] = v * scale;
        }
  }
}

// reduce 4 f32 split-K partials -> Gbf bf16. grid (64, B), block 256
__global__ __launch_bounds__(256) void reduceG_kernel(
    const float* __restrict__ Gp, u16* __restrict__ G) {
  int b = blockIdx.y;
  int e = blockIdx.x * 1024 + threadIdx.x * 4;
  const float* base = Gp + (long)b * 262144;
  float4 s = *(const float4*)(base + e);
#pragma unroll
  for (int sl = 1; sl < 4; ++sl) {
    float4 v = *(const float4*)(base + sl * 65536 + e);
    s.x += v.x; s.y += v.y; s.z += v.z; s.w += v.w;
  }
  ushort4 o;
  o.x = f2b(s.x); o.y = f2b(s.y); o.z = f2b(s.z); o.w = f2b(s.w);
  *(ushort4*)(G + (long)b * 65536 + e) = o;
}

// ---------------------------------------------------------------------------
// softmax over rows of S -> attn^T bf16 (attnT[d][c] = attn[c][d])
__global__ __launch_bounds__(256) void softmax_kernel(const float* __restrict__ S,
                                                      u16* __restrict__ attnT) {
  int row = blockIdx.x;
  int t = threadIdx.x;
  float v = S[(long)row * C + t];
  __shared__ float red[256];
  red[t] = v; __syncthreads();
  for (int st = 128; st > 0; st >>= 1) {
    if (t < st) red[t] = fmaxf(red[t], red[t + st]);
    __syncthreads();
  }
  float mx = red[0];
  __syncthreads();
  float e = __expf(v - mx);
  red[t] = e; __syncthreads();
  for (int st = 128; st > 0; st >>= 1) {
    if (t < st) red[t] += red[t + st];
    __syncthreads();
  }
  float inv = 1.0f / red[0];
  int b = row >> 8, c = row & 255;
  attnT[(long)b * 65536 + t * 256 + c] = f2b(e * inv);
}

// cbias[b][j] = proj_b[j] + sum_d M[b][j][d]*qkv_b[512+d]
__global__ __launch_bounds__(256) void cbias_kernel(const u16* __restrict__ M,
                                                    const float* __restrict__ qkv_b,
                                                    const float* __restrict__ proj_b,
                                                    float* __restrict__ cb) {
  int b = blockIdx.x, j = threadIdx.x;
  const u16* m = M + (long)b * 65536 + (long)j * 256;
  float s = 0.f;
  for (int d = 0; d < C; ++d) s += b2f(m[d]) * qkv_b[512 + d];
  cb[b * C + j] = proj_b[j] + s;
}

// ---------------------------------------------------------------------------
// Fused conv3x3 implicit-GEMM + attention-output GEMM.
// Round-2 proven shape: 128x128 tile, BK=32, 4 waves (2Mx2N), acc[4][4],
// merged conv+attn accumulator (fragment aliasing proven r3/r4).
// NEW vs r2: 3-stage LDS pipeline with counted vmcnt (T3/T4) — per step,
// STAGE(t+2) issues 4 glds/wave which stay in flight across the barrier;
// s_waitcnt vmcnt(4) drains only stage t+1. LDS 48KB -> 3 blocks/CU.
// K = 72 conv steps (9 taps x 256 ch) + 8 attn steps (K=256).
__global__ __launch_bounds__(256, 2) void convattn_kernel(
    const u16* __restrict__ xT, const u16* __restrict__ cw,
    const u16* __restrict__ W2, const u16* __restrict__ zbuf,
    const float* __restrict__ conv_b, const float* __restrict__ cb,
    float* __restrict__ out) {
  int b = blockIdx.y;
  int to = blockIdx.x >> 5;  // 0..1
  int tn = blockIdx.x & 31;  // 0..31
  int row0 = to * 128, col0 = tn * 128;
  const u16* xTb = xT + (long)b * CN;
  const u16* W2b = W2 + (long)b * 65536;

  __shared__ u16 lA[3][4096];   // 3 x 8KB A-tiles [128][32]
  __shared__ u16 lB[3][4096];   // 3 x 8KB B-tiles [128][32]

  int tid = threadIdx.x;
  int lane = tid & 63, wv = tid >> 6;
  int wm = wv >> 1, wn = wv & 1;
  int fr = lane & 15, kq = lane >> 4;
  int kqs = kq ^ ((fr >> 1) & 3);

  // staging chunks: c0 = wv*128+lane, c1 = c0+64 (16B each)
  int c0 = wv * 128 + lane, c1 = c0 + 64;
  int r0s = c0 >> 2, r1s = c1 >> 2;
  int ls0 = (c0 & 3) ^ ((r0s >> 1) & 3);
  int ls1 = (c1 & 3) ^ ((r1s >> 1) & 3);
  int dst0 = wv * 1024, dst1 = wv * 1024 + 512;

  // conv A (weights), conv B (tokens)
  const u16* pA0 = cw + (long)(row0 + r0s) * 2304 + ls0 * 8;
  const u16* pA1 = cw + (long)(row0 + r1s) * 2304 + ls1 * 8;
  int t0 = col0 + r0s, t1 = col0 + r1s;
  int h0 = t0 >> 6, w0_ = t0 & 63, h1 = t1 >> 6, w1_ = t1 & 63;
  const u16* pB0 = xTb + (long)t0 * 256 + ls0 * 8;
  const u16* pB1 = xTb + (long)t1 * 256 + ls1 * 8;
  const u16* zs0 = zbuf + ls0 * 8;
  const u16* zs1 = zbuf + ls1 * 8;
  // attn A (gathered xT rows, stride-16 tokens), attn B (W2 rows)
  int nb = col0 >> 8, jb = col0 & 255;
  const u16* qA0 = xTb + (long)((row0 + r0s) * 16 + nb) * 256 + ls0 * 8;
  const u16* qA1 = xTb + (long)((row0 + r1s) * 16 + nb) * 256 + ls1 * 8;
  const u16* qB0 = W2b + (long)(jb + r0s) * 256 + ls0 * 8;
  const u16* qB1 = W2b + (long)(jb + r1s) * 256 + ls1 * 8;

  f32x4 acc[4][4] = {};

  auto STAGE = [&](int buf, int t) {
    if (t < 72) {
      int tap = t >> 3, i0 = (t & 7) << 5;
      int dh = tap / 3 - 1, dw = tap % 3 - 1;
      glds16(pA0 + tap * 256 + i0, &lA[buf][dst0]);
      glds16(pA1 + tap * 256 + i0, &lA[buf][dst1]);
      long sh = (long)(dh * 64 + dw) * 256 + i0;
      bool v0 = ((unsigned)(h0 + dh) < 64u) && ((unsigned)(w0_ + dw) < 64u);
      bool v1 = ((unsigned)(h1 + dh) < 64u) && ((unsigned)(w1_ + dw) < 64u);
      glds16(v0 ? pB0 + sh : zs0, &lB[buf][dst0]);
      glds16(v1 ? pB1 + sh : zs1, &lB[buf][dst1]);
    } else {
      int k0 = (t - 72) << 5;
      glds16(qA0 + k0, &lA[buf][dst0]);
      glds16(qA1 + k0, &lA[buf][dst1]);
      glds16(qB0 + k0, &lB[buf][dst0]);
      glds16(qB1 + k0, &lB[buf][dst1]);
    }
  };
  auto COMPUTE = [&](int buf) {
    bf16x8 af[4], bfr[4];
#pragma unroll
    for (int m = 0; m < 4; ++m)
      af[m] = *(const bf16x8*)&lA[buf][(wm * 64 + m * 16 + fr) * 32 + kqs * 8];
#pragma unroll
    for (int n = 0; n < 4; ++n)
      bfr[n] = *(const bf16x8*)&lB[buf][(wn * 64 + n * 16 + fr) * 32 + kqs * 8];
    __builtin_amdgcn_s_setprio(1);
#pragma unroll
    for (int m = 0; m < 4; ++m)
#pragma unroll
      for (int n = 0; n < 4; ++n)
        acc[m][n] = __builtin_amdgcn_mfma_f32_16x16x32_bf16(af[m], bfr[n], acc[m][n], 0, 0, 0);
    __builtin_amdgcn_s_setprio(0);
  };

  // prologue: 2 stages in flight; wait only for stage 0 (4 loads remain)
  STAGE(0, 0);
  STAGE(1, 1);
  asm volatile("s_waitcnt vmcnt(4)" ::: "memory");
  __builtin_amdgcn_sched_barrier(0);
  __builtin_amdgcn_s_barrier();
  __builtin_amdgcn_sched_barrier(0);

  int cur = 0;
  for (int t = 0; t < 80; ++t) {
    int nxt = cur + 2; if (nxt >= 3) nxt -= 3;
    if (t + 2 < 80) {
      STAGE(nxt, t + 2);           // issue-early; stays in flight past barrier
      COMPUTE(cur);
      asm volatile("s_waitcnt vmcnt(4)" ::: "memory");  // drain t+1 only
    } else {
      COMPUTE(cur);
      asm volatile("s_waitcnt vmcnt(0)" ::: "memory");  // tail drain
    }
    __builtin_amdgcn_sched_barrier(0);
    __builtin_amdgcn_s_barrier();
    __builtin_amdgcn_sched_barrier(0);
    cur = (cur + 1 == 3) ? 0 : cur + 1;
  }

  float* ob = out + (long)b * CN;
  const float* cbb = cb + b * C;
#pragma unroll
  for (int m = 0; m < 4; ++m) {
    int go = row0 + wm * 64 + m * 16 + kq * 4;
#pragma unroll
    for (int nn = 0; nn < 4; ++nn) {
      int cc = wn * 64 + nn * 16 + fr;
      float cbv = cbb[jb + cc];
#pragma unroll
      for (int r = 0; r < 4; ++r)
        ob[(long)(go + r) * NTOK + col0 + cc] =
            acc[m][nn][r] + conv_b[go + r] + cbv;
    }
  }
}

// ---------------------------------------------------------------------------
extern "C" void kernel_launch(void* const* d_in, const int* in_sizes, int n_in,
                              void* d_out, int out_size, void* d_ws, size_t ws_size,
                              hipStream_t stream) {
  const float* x = (const float*)d_in[0];
  const float* qkv_w = (const float*)d_in[1];
  const float* qkv_b = (const float*)d_in[2];
  const float* proj_w = (const float*)d_in[3];
  const float* proj_b = (const float*)d_in[4];
  const float* conv_w = (const float*)d_in[5];
  const float* conv_b = (const float*)d_in[6];
  float* out = (float*)d_out;
  char* ws = (char*)d_ws;

  u16* xbf = (u16*)(ws);                    // 32 MB
  u16* xT = (u16*)(ws + 33554432);          // 32 MB
  u16* Gbf = (u16*)(ws + 67108864);         // 2 MB
  // union region: Gpart (16.7 MB, dead after reduceG) overlaps the small
  // intermediates created afterwards.
  float* Gpart = (float*)(ws + 69206016);
  u16* T1bf = (u16*)(ws + 69206016);
  float* Sf = (float*)(ws + 71303168);
  u16* attnT = (u16*)(ws + 75497472);
  u16* Mbf = (u16*)(ws + 77594624);
  u16* W2bf = (u16*)(ws + 79691776);
  u16* Wq = (u16*)(ws + 85983232);
  u16* Wk = (u16*)(ws + 86114304);
  u16* WvT = (u16*)(ws + 86245376);
  u16* Pw = (u16*)(ws + 86376448);
  u16* cw = (u16*)(ws + 86507520);
  float* rws = (float*)(ws + 87687168);
  float* uws = (float*)(ws + 87703552);
  float* wws = (float*)(ws + 87719936);
  float* cb = (float*)(ws + 87736320);
  u16* zbuf = (u16*)(ws + 87752704);

  prep_w_kernel<<<3328, 256, 0, stream>>>(qkv_w, proj_w, conv_w, Wq, Wk, WvT,
                                          Pw, cw, rws, zbuf);
  prep_x_kernel<<<dim3(128, 8, BATCH), 256, 0, stream>>>(x, xbf, xT, rws);
  bias_uw_kernel<<<BATCH, 512, 0, stream>>>(qkv_w, rws, uws, wws);

  // G = X*X^T per batch, split-K x4 -> f32 partials
  gemm_glds_kernel<0><<<dim3(4, 4, BATCH), 256, 0, stream>>>(
      xbf, xbf, Gpart, 1024, 4096, 4096, 256, 2, CN, CN, 65536,
      0.f, nullptr, nullptr, nullptr, nullptr, 0);
  reduceG_kernel<<<dim3(64, BATCH), 256, 0, stream>>>(Gpart, Gbf);

  // T1 = Wq * G  (G symmetric)
  gemm_glds_kernel<1><<<dim3(4, 1, BATCH), 256, 0, stream>>>(
      Wq, Gbf, T1bf, 256, 256, 256, 256, 2, 0, 65536, 65536,
      0.f, nullptr, nullptr, nullptr, nullptr, 0);
  // S = (T1 * Wk^T + bias terms) * scale
  gemm_glds_kernel<2><<<dim3(4, 1, BATCH), 256, 0, stream>>>(
      T1bf, Wk, Sf, 256, 256, 256, 256, 2, 65536, 0, 65536,
      0.0625f, qkv_b, qkv_b + 256, uws, wws, 256);

  softmax_kernel<<<BATCH * C, 256, 0, stream>>>(Sf, attnT);

  // M = Pw * attn   (B operand = attn^T)
  gemm_glds_kernel<1><<<dim3(4, 1, BATCH), 256, 0, stream>>>(
      Pw, attnT, Mbf, 256, 256, 256, 256, 2, 0, 65536, 65536,
      0.f, nullptr, nullptr, nullptr, nullptr, 0);
  cbias_kernel<<<BATCH, 256, 0, stream>>>(Mbf, qkv_b, proj_b, cb);
  // W2 = M * Wv     (B operand = WvT)
  gemm_glds_kernel<1><<<dim3(4, 1, BATCH), 256, 0, stream>>>(
      Mbf, WvT, W2bf, 256, 256, 256, 256, 2, 65536, 0, 65536,
      0.f, nullptr, nullptr, nullptr, nullptr, 0);

  // fused conv + attention-output, single store of out
  convattn_kernel<<<dim3(64, BATCH), 256, 0, stream>>>(xT, cw, W2bf, zbuf,
                                                       conv_b, cb, out);
}

// Round 6
// 236.018 us; speedup vs baseline: 2.4660x; 1.1036x over previous
//
#include <hip/hip_runtime.h>
#include <hip/hip_bf16.h>

typedef unsigned short u16;
typedef __bf16 bf16x8 __attribute__((ext_vector_type(8)));
typedef float f32x4 __attribute__((ext_vector_type(4)));

#define BATCH 16
#define C 256
#define NTOK 4096      // H*W
#define CN 1048576     // C*NTOK

__device__ __forceinline__ u16 f2b(float f) {
  __hip_bfloat16 h = __float2bfloat16(f);
  return __builtin_bit_cast(u16, h);
}
__device__ __forceinline__ float b2f(u16 u) {
  unsigned int x = ((unsigned int)u) << 16;
  return __builtin_bit_cast(float, x);
}

// async global->LDS, 16B per lane. LDS dest must be wave-uniform base
// (HW adds lane*16); global src is per-lane.
__device__ __forceinline__ void glds16(const u16* g, u16* l) {
  __builtin_amdgcn_global_load_lds(
      (const __attribute__((address_space(1))) unsigned int*)(g),
      (__attribute__((address_space(3))) unsigned int*)(l), 16, 0, 0);
}

// ---------------------------------------------------------------------------
// prep_x: x f32 [B][C][N] -> xbf [B][C][N], xT [B][N][C]; row partial sums
// atomically into rws (rws zeroed by prep_w, launched before).
// grid (128, 8, B), block 256
__global__ __launch_bounds__(256) void prep_x_kernel(
    const float* __restrict__ x, u16* __restrict__ xbf, u16* __restrict__ xT,
    float* __restrict__ rws) {
  __shared__ float t[32][33];
  int b = blockIdx.z;
  int c0 = blockIdx.y * 32, n0 = blockIdx.x * 32;
  int tid = threadIdx.x;
  int i = tid >> 3, j4 = (tid & 7) * 4;
  const float* xb = x + (long)b * CN;
  float4 v = *(const float4*)(xb + (long)(c0 + i) * NTOK + n0 + j4);
  ushort4 bv;
  bv.x = f2b(v.x); bv.y = f2b(v.y); bv.z = f2b(v.z); bv.w = f2b(v.w);
  *(ushort4*)(xbf + (long)b * CN + (long)(c0 + i) * NTOK + n0 + j4) = bv;
  t[i][j4 + 0] = v.x; t[i][j4 + 1] = v.y; t[i][j4 + 2] = v.z; t[i][j4 + 3] = v.w;
  __syncthreads();
  ushort4 o;
  o.x = f2b(t[j4 + 0][i]); o.y = f2b(t[j4 + 1][i]);
  o.z = f2b(t[j4 + 2][i]); o.w = f2b(t[j4 + 3][i]);
  *(ushort4*)(xT + (long)b * CN + (long)(n0 + i) * C + c0 + j4) = o;
  if (tid < 32) {
    float s = 0.f;
#pragma unroll
    for (int j = 0; j < 32; ++j) s += t[tid][j];
    atomicAdd(&rws[b * C + c0 + tid], s);
  }
}

// ---------------------------------------------------------------------------
// prep_w: bf16-convert weights; WvT transposed; conv w reordered [o][tap][i];
// also zeroes rws and zbuf. grid 3328 x 256.
__global__ __launch_bounds__(256) void prep_w_kernel(
    const float* __restrict__ qkv_w, const float* __restrict__ proj_w,
    const float* __restrict__ conv_w, u16* __restrict__ Wq, u16* __restrict__ Wk,
    u16* __restrict__ WvT, u16* __restrict__ Pw, u16* __restrict__ cw,
    float* __restrict__ rws, u16* __restrict__ zbuf) {
  int idx = blockIdx.x * 256 + threadIdx.x;
  if (idx < 4096) rws[idx] = 0.f;
  if (idx < 256) zbuf[idx] = 0;
  if (idx < 65536) {
    Wq[idx] = f2b(qkv_w[idx]);
  } else if (idx < 131072) {
    int e = idx - 65536;
    Wk[e] = f2b(qkv_w[65536 + e]);
  } else if (idx < 196608) {
    int e = idx - 131072;
    int i = e >> 8, d = e & 255;
    WvT[e] = f2b(qkv_w[131072 + d * 256 + i]);
  } else if (idx < 262144) {
    int e = idx - 196608;
    Pw[e] = f2b(proj_w[e]);
  } else if (idx < 851968) {
    int e = idx - 262144;
    int o = e / 2304;
    int rem = e - o * 2304;
    int tap = rem >> 8, i = rem & 255;
    cw[e] = f2b(conv_w[o * 2304 + i * 9 + tap]);
  }
}

// bias_uw: u[b][d] = Wk[d,:]*r[b,:] ; w[b][c] = Wq[c,:]*r[b,:]
__global__ __launch_bounds__(512) void bias_uw_kernel(
    const float* __restrict__ qkv_w, const float* __restrict__ r,
    float* __restrict__ u, float* __restrict__ w) {
  int b = blockIdx.x, t = threadIdx.x;
  const float* rb = r + b * C;
  if (t < 256) {
    float s = 0.f;
    for (int i = 0; i < C; ++i) s += qkv_w[(256 + t) * 256 + i] * rb[i];
    u[b * C + t] = s;
  } else {
    int c = t - 256;
    float s = 0.f;
    for (int i = 0; i < C; ++i) s += qkv_w[c * 256 + i] * rb[i];
    w[b * C + c] = s;
  }
}

// ---------------------------------------------------------------------------
// Generic GEMM C = A*B^T (both K-contiguous), 128x128 tile, BK=32, 4 waves,
// global_load_lds staging + slot-XOR swizzle, double-buffered.
// grid (tilesM*tilesN, ksplit, batch)
// EPI 0: f32 partial store at (b*gridDim.y+ks)*sC. EPI 1: bf16. EPI 2: S-epi.
template <int EPI>
__global__ __launch_bounds__(256, 2) void gemm_glds_kernel(
    const u16* __restrict__ A, const u16* __restrict__ B, void* __restrict__ Cv,
    int K, int lda, int ldb, int ldc, int tilesN, long sA, long sB, long sC,
    float scale, const float* __restrict__ e1, const float* __restrict__ e2,
    const float* __restrict__ e3, const float* __restrict__ e4, int e34stride) {
  int b = blockIdx.z, ks = blockIdx.y;
  A += (long)b * sA + (long)ks * K;
  B += (long)b * sB + (long)ks * K;
  int ty = blockIdx.x / tilesN, tx = blockIdx.x % tilesN;
  int row0 = ty * 128, col0 = tx * 128;

  __shared__ u16 lA[2][4096];
  __shared__ u16 lB[2][4096];

  int tid = threadIdx.x;
  int lane = tid & 63, wv = tid >> 6;
  int wm = wv >> 1, wn = wv & 1;
  int fr = lane & 15, kq = lane >> 4;
  int kqs = kq ^ ((fr >> 1) & 3);

  // staging chunks: c0 = wv*128+lane, c1 = c0+64 (16B each)
  int c0 = wv * 128 + lane, c1 = c0 + 64;
  int r0s = c0 >> 2, r1s = c1 >> 2;
  int ls0 = (c0 & 3) ^ ((r0s >> 1) & 3);
  int ls1 = (c1 & 3) ^ ((r1s >> 1) & 3);
  const u16* pA0 = A + (long)(row0 + r0s) * lda + ls0 * 8;
  const u16* pA1 = A + (long)(row0 + r1s) * lda + ls1 * 8;
  const u16* pB0 = B + (long)(col0 + r0s) * ldb + ls0 * 8;
  const u16* pB1 = B + (long)(col0 + r1s) * ldb + ls1 * 8;
  int dst0 = wv * 1024, dst1 = wv * 1024 + 512;

  f32x4 acc[4][4] = {};

  auto STAGE = [&](int buf, int t) {
    int k0 = t << 5;
    glds16(pA0 + k0, &lA[buf][dst0]);
    glds16(pA1 + k0, &lA[buf][dst1]);
    glds16(pB0 + k0, &lB[buf][dst0]);
    glds16(pB1 + k0, &lB[buf][dst1]);
  };
  auto COMPUTE = [&](int buf) {
    bf16x8 af[4], bfr[4];
#pragma unroll
    for (int m = 0; m < 4; ++m)
      af[m] = *(const bf16x8*)&lA[buf][(wm * 64 + m * 16 + fr) * 32 + kqs * 8];
#pragma unroll
    for (int n = 0; n < 4; ++n)
      bfr[n] = *(const bf16x8*)&lB[buf][(wn * 64 + n * 16 + fr) * 32 + kqs * 8];
#pragma unroll
    for (int m = 0; m < 4; ++m)
#pragma unroll
      for (int n = 0; n < 4; ++n)
        acc[m][n] = __builtin_amdgcn_mfma_f32_16x16x32_bf16(af[m], bfr[n], acc[m][n], 0, 0, 0);
  };

  int nk = K >> 5, cur = 0;
  STAGE(0, 0);
  __syncthreads();
  for (int t = 0; t < nk; ++t) {
    if (t + 1 < nk) STAGE(cur ^ 1, t + 1);
    COMPUTE(cur);
    __syncthreads();
    cur ^= 1;
  }

  if (EPI == 0) {
    float* Cb = (float*)Cv + ((long)b * gridDim.y + ks) * sC;
#pragma unroll
    for (int m = 0; m < 4; ++m)
#pragma unroll
      for (int n = 0; n < 4; ++n)
#pragma unroll
        for (int r = 0; r < 4; ++r) {
          int gr = row0 + wm * 64 + m * 16 + kq * 4 + r;
          int gc = col0 + wn * 64 + n * 16 + fr;
          Cb[(long)gr * ldc + gc] = acc[m][n][r];
        }
  } else if (EPI == 1) {
    __hip_bfloat16* Cb = (__hip_bfloat16*)Cv + (long)b * sC;
#pragma unroll
    for (int m = 0; m < 4; ++m)
#pragma unroll
      for (int n = 0; n < 4; ++n)
#pragma unroll
        for (int r = 0; r < 4; ++r) {
          int gr = row0 + wm * 64 + m * 16 + kq * 4 + r;
          int gc = col0 + wn * 64 + n * 16 + fr;
          Cb[(long)gr * ldc + gc] = __float2bfloat16(acc[m][n][r]);
        }
  } else if (EPI == 2) {
    float* Cb = (float*)Cv + (long)b * sC;
    const float* ub = e3 + (long)b * e34stride;
    const float* wb = e4 + (long)b * e34stride;
#pragma unroll
    for (int m = 0; m < 4; ++m)
#pragma unroll
      for (int n = 0; n < 4; ++n)
#pragma unroll
        for (int r = 0; r < 4; ++r) {
          int gr = row0 + wm * 64 + m * 16 + kq * 4 + r;
          int gc = col0 + wn * 64 + n * 16 + fr;
          float v = acc[m][n][r] + e1[gr] * ub[gc] + e2[gc] * wb[gr] +
                    4096.0f * e1[gr] * e2[gc];
          Cb[(long)gr * ldc + gc] = v * scale;
        }
  }
}

// reduce 4 f32 split-K partials -> Gbf bf16. grid (64, B), block 256
__global__ __launch_bounds__(256) void reduceG_kernel(
    const float* __restrict__ Gp, u16* __restrict__ G) {
  int b = blockIdx.y;
  int e = blockIdx.x * 1024 + threadIdx.x * 4;
  const float* base = Gp + (long)b * 262144;
  float4 s = *(const float4*)(base + e);
#pragma unroll
  for (int sl = 1; sl < 4; ++sl) {
    float4 v = *(const float4*)(base + sl * 65536 + e);
    s.x += v.x; s.y += v.y; s.z += v.z; s.w += v.w;
  }
  ushort4 o;
  o.x = f2b(s.x); o.y = f2b(s.y); o.z = f2b(s.z); o.w = f2b(s.w);
  *(ushort4*)(G + (long)b * 65536 + e) = o;
}

// ---------------------------------------------------------------------------
// softmax over rows of S -> attn^T bf16 (attnT[d][c] = attn[c][d])
__global__ __launch_bounds__(256) void softmax_kernel(const float* __restrict__ S,
                                                      u16* __restrict__ attnT) {
  int row = blockIdx.x;
  int t = threadIdx.x;
  float v = S[(long)row * C + t];
  __shared__ float red[256];
  red[t] = v; __syncthreads();
  for (int st = 128; st > 0; st >>= 1) {
    if (t < st) red[t] = fmaxf(red[t], red[t + st]);
    __syncthreads();
  }
  float mx = red[0];
  __syncthreads();
  float e = __expf(v - mx);
  red[t] = e; __syncthreads();
  for (int st = 128; st > 0; st >>= 1) {
    if (t < st) red[t] += red[t + st];
    __syncthreads();
  }
  float inv = 1.0f / red[0];
  int b = row >> 8, c = row & 255;
  attnT[(long)b * 65536 + t * 256 + c] = f2b(e * inv);
}

// cbias[b][j] = proj_b[j] + sum_d M[b][j][d]*qkv_b[512+d]
__global__ __launch_bounds__(256) void cbias_kernel(const u16* __restrict__ M,
                                                    const float* __restrict__ qkv_b,
                                                    const float* __restrict__ proj_b,
                                                    float* __restrict__ cb) {
  int b = blockIdx.x, j = threadIdx.x;
  const u16* m = M + (long)b * 65536 + (long)j * 256;
  float s = 0.f;
  for (int d = 0; d < C; ++d) s += b2f(m[d]) * qkv_b[512 + d];
  cb[b * C + j] = proj_b[j] + s;
}

// ---------------------------------------------------------------------------
// Fused conv3x3 implicit-GEMM + attention-output GEMM.
// 128x128 tile, BK=32, 4 waves, acc[4][4]; merged conv+attn accumulator.
// Loop restructured as 9 conv taps + 1 peeled attn tap, 8 chunks each,
// inner fully unrolled: staging sources are tap_base + STATIC chunk offset
// (folds into the load's imm offset -> ~zero per-step VALU), tap math
// (div/mod 3, bounds checks, cndmask selects) hoisted to once per tap.
// 4 LDS buffers (64KB): buffer index (j+2)&3 is static since 4 | 8.
// Counted vmcnt(4): stage t+2 stays in flight across the barrier (T3/T4).
__global__ __launch_bounds__(256, 2) void convattn_kernel(
    const u16* __restrict__ xT, const u16* __restrict__ cw,
    const u16* __restrict__ W2, const u16* __restrict__ zbuf,
    const float* __restrict__ conv_b, const float* __restrict__ cb,
    float* __restrict__ out) {
  int b = blockIdx.y;
  int to = blockIdx.x >> 5;  // 0..1
  int tn = blockIdx.x & 31;  // 0..31
  int row0 = to * 128, col0 = tn * 128;
  const u16* xTb = xT + (long)b * CN;
  const u16* W2b = W2 + (long)b * 65536;

  __shared__ u16 lA[4][4096];   // 4 x 8KB A-tiles [128][32]
  __shared__ u16 lB[4][4096];   // 4 x 8KB B-tiles [128][32]

  int tid = threadIdx.x;
  int lane = tid & 63, wv = tid >> 6;
  int wm = wv >> 1, wn = wv & 1;
  int fr = lane & 15, kq = lane >> 4;
  int kqs = kq ^ ((fr >> 1) & 3);

  // staging chunks: c0 = wv*128+lane, c1 = c0+64 (16B each)
  int c0 = wv * 128 + lane, c1 = c0 + 64;
  int r0s = c0 >> 2, r1s = c1 >> 2;
  int ls0 = (c0 & 3) ^ ((r0s >> 1) & 3);
  int ls1 = (c1 & 3) ^ ((r1s >> 1) & 3);
  int dst0 = wv * 1024, dst1 = wv * 1024 + 512;

  // per-thread fixed bases (tap-independent parts)
  const u16* pA0 = cw + (long)(row0 + r0s) * 2304 + ls0 * 8;
  const u16* pA1 = cw + (long)(row0 + r1s) * 2304 + ls1 * 8;
  int t0 = col0 + r0s, t1 = col0 + r1s;
  int h0 = t0 >> 6, w0_ = t0 & 63, h1 = t1 >> 6, w1_ = t1 & 63;
  const u16* pB0 = xTb + (long)t0 * 256 + ls0 * 8;
  const u16* pB1 = xTb + (long)t1 * 256 + ls1 * 8;
  const u16* zs0 = zbuf + ls0 * 8;
  const u16* zs1 = zbuf + ls1 * 8;
  int nb = col0 >> 8, jb = col0 & 255;
  const u16* qA0 = xTb + (long)((row0 + r0s) * 16 + nb) * 256 + ls0 * 8;
  const u16* qA1 = xTb + (long)((row0 + r1s) * 16 + nb) * 256 + ls1 * 8;
  const u16* qB0 = W2b + (long)(jb + r0s) * 256 + ls0 * 8;
  const u16* qB1 = W2b + (long)(jb + r1s) * 256 + ls1 * 8;

  f32x4 acc[4][4] = {};

  // tap base pointers: cur = tap being staged chunks 2..7; nxt = next tap
  const u16 *a0c, *a1c, *b0c, *b1c, *a0n, *a1n, *b0n, *b1n;
  auto conv_bases = [&](int tap, const u16*& a0, const u16*& a1,
                        const u16*& b0, const u16*& b1) {
    int dh = tap / 3 - 1, dw = tap % 3 - 1;
    a0 = pA0 + tap * 256;
    a1 = pA1 + tap * 256;
    long sh = (long)(dh * 64 + dw) * 256;
    bool v0 = ((unsigned)(h0 + dh) < 64u) && ((unsigned)(w0_ + dw) < 64u);
    bool v1 = ((unsigned)(h1 + dh) < 64u) && ((unsigned)(w1_ + dw) < 64u);
    b0 = v0 ? pB0 + sh : zs0;
    b1 = v1 ? pB1 + sh : zs1;
  };

  auto COMPUTE = [&](int buf) {
    bf16x8 af[4], bfr[4];
#pragma unroll
    for (int m = 0; m < 4; ++m)
      af[m] = *(const bf16x8*)&lA[buf][(wm * 64 + m * 16 + fr) * 32 + kqs * 8];
#pragma unroll
    for (int n = 0; n < 4; ++n)
      bfr[n] = *(const bf16x8*)&lB[buf][(wn * 64 + n * 16 + fr) * 32 + kqs * 8];
    __builtin_amdgcn_s_setprio(1);
#pragma unroll
    for (int m = 0; m < 4; ++m)
#pragma unroll
      for (int n = 0; n < 4; ++n)
        acc[m][n] = __builtin_amdgcn_mfma_f32_16x16x32_bf16(af[m], bfr[n], acc[m][n], 0, 0, 0);
    __builtin_amdgcn_s_setprio(0);
  };

  conv_bases(0, a0c, a1c, b0c, b1c);
  conv_bases(1, a0n, a1n, b0n, b1n);

  // prologue: stage tap0 chunks 0,1 into bufs 0,1; wait for chunk 0 only
  glds16(a0c + 0, &lA[0][dst0]);
  glds16(a1c + 0, &lA[0][dst1]);
  glds16(b0c + 0, &lB[0][dst0]);
  glds16(b1c + 0, &lB[0][dst1]);
  glds16(a0c + 32, &lA[1][dst0]);
  glds16(a1c + 32, &lA[1][dst1]);
  glds16(b0c + 32, &lB[1][dst0]);
  glds16(b1c + 32, &lB[1][dst1]);
  asm volatile("s_waitcnt vmcnt(4)" ::: "memory");
  __builtin_amdgcn_sched_barrier(0);
  __builtin_amdgcn_s_barrier();
  __builtin_amdgcn_sched_barrier(0);

#pragma unroll 1
  for (int T = 0; T < 9; ++T) {
#pragma unroll
    for (int j = 0; j < 8; ++j) {
      // stage step s = 8T+j+2: chunks 2..7 of cur tap, then 0..1 of next
      const int bs = (j + 2) & 3;                  // static
      const int cofs = (j < 6) ? (j + 2) * 32 : (j - 6) * 32;  // static
      const u16* sa0 = (j < 6) ? a0c : a0n;
      const u16* sa1 = (j < 6) ? a1c : a1n;
      const u16* sb0 = (j < 6) ? b0c : b0n;
      const u16* sb1 = (j < 6) ? b1c : b1n;
      glds16(sa0 + cofs, &lA[bs][dst0]);
      glds16(sa1 + cofs, &lA[bs][dst1]);
      glds16(sb0 + cofs, &lB[bs][dst0]);
      glds16(sb1 + cofs, &lB[bs][dst1]);
      COMPUTE(j & 3);
      asm volatile("s_waitcnt vmcnt(4)" ::: "memory");  // drain step t+1 only
      __builtin_amdgcn_sched_barrier(0);
      __builtin_amdgcn_s_barrier();
      __builtin_amdgcn_sched_barrier(0);
    }
    a0c = a0n; a1c = a1n; b0c = b0n; b1c = b1n;
    if (T < 7) {
      conv_bases(T + 2, a0n, a1n, b0n, b1n);
    } else {
      a0n = qA0; a1n = qA1; b0n = qB0; b1n = qB1;
    }
  }

  // peeled attn tap (steps 72..79); cur = attn bases
#pragma unroll
  for (int j = 0; j < 6; ++j) {
    const int bs = (j + 2) & 3;
    const int cofs = (j + 2) * 32;
    glds16(a0c + cofs, &lA[bs][dst0]);
    glds16(a1c + cofs, &lA[bs][dst1]);
    glds16(b0c + cofs, &lB[bs][dst0]);
    glds16(b1c + cofs, &lB[bs][dst1]);
    COMPUTE(j & 3);
    asm volatile("s_waitcnt vmcnt(4)" ::: "memory");
    __builtin_amdgcn_sched_barrier(0);
    __builtin_amdgcn_s_barrier();
    __builtin_amdgcn_sched_barrier(0);
  }
  COMPUTE(2);
  asm volatile("s_waitcnt vmcnt(0)" ::: "memory");
  __builtin_amdgcn_sched_barrier(0);
  __builtin_amdgcn_s_barrier();
  __builtin_amdgcn_sched_barrier(0);
  COMPUTE(3);

  float* ob = out + (long)b * CN;
  const float* cbb = cb + b * C;
#pragma unroll
  for (int m = 0; m < 4; ++m) {
    int go = row0 + wm * 64 + m * 16 + kq * 4;
#pragma unroll
    for (int nn = 0; nn < 4; ++nn) {
      int cc = wn * 64 + nn * 16 + fr;
      float cbv = cbb[jb + cc];
#pragma unroll
      for (int r = 0; r < 4; ++r)
        ob[(long)(go + r) * NTOK + col0 + cc] =
            acc[m][nn][r] + conv_b[go + r] + cbv;
    }
  }
}

// ---------------------------------------------------------------------------
extern "C" void kernel_launch(void* const* d_in, const int* in_sizes, int n_in,
                              void* d_out, int out_size, void* d_ws, size_t ws_size,
                              hipStream_t stream) {
  const float* x = (const float*)d_in[0];
  const float* qkv_w = (const float*)d_in[1];
  const float* qkv_b = (const float*)d_in[2];
  const float* proj_w = (const float*)d_in[3];
  const float* proj_b = (const float*)d_in[4];
  const float* conv_w = (const float*)d_in[5];
  const float* conv_b = (const float*)d_in[6];
  float* out = (float*)d_out;
  char* ws = (char*)d_ws;

  u16* xbf = (u16*)(ws);                    // 32 MB
  u16* xT = (u16*)(ws + 33554432);          // 32 MB
  u16* Gbf = (u16*)(ws + 67108864);         // 2 MB
  // union region: Gpart (16.7 MB, dead after reduceG) overlaps the small
  // intermediates created afterwards.
  float* Gpart = (float*)(ws + 69206016);
  u16* T1bf = (u16*)(ws + 69206016);
  float* Sf = (float*)(ws + 71303168);
  u16* attnT = (u16*)(ws + 75497472);
  u16* Mbf = (u16*)(ws + 77594624);
  u16* W2bf = (u16*)(ws + 79691776);
  u16* Wq = (u16*)(ws + 85983232);
  u16* Wk = (u16*)(ws + 86114304);
  u16* WvT = (u16*)(ws + 86245376);
  u16* Pw = (u16*)(ws + 86376448);
  u16* cw = (u16*)(ws + 86507520);
  float* rws = (float*)(ws + 87687168);
  float* uws = (float*)(ws + 87703552);
  float* wws = (float*)(ws + 87719936);
  float* cb = (float*)(ws + 87736320);
  u16* zbuf = (u16*)(ws + 87752704);

  prep_w_kernel<<<3328, 256, 0, stream>>>(qkv_w, proj_w, conv_w, Wq, Wk, WvT,
                                          Pw, cw, rws, zbuf);
  prep_x_kernel<<<dim3(128, 8, BATCH), 256, 0, stream>>>(x, xbf, xT, rws);
  bias_uw_kernel<<<BATCH, 512, 0, stream>>>(qkv_w, rws, uws, wws);

  // G = X*X^T per batch, split-K x4 -> f32 partials
  gemm_glds_kernel<0><<<dim3(4, 4, BATCH), 256, 0, stream>>>(
      xbf, xbf, Gpart, 1024, 4096, 4096, 256, 2, CN, CN, 65536,
      0.f, nullptr, nullptr, nullptr, nullptr, 0);
  reduceG_kernel<<<dim3(64, BATCH), 256, 0, stream>>>(Gpart, Gbf);

  // T1 = Wq * G  (G symmetric)
  gemm_glds_kernel<1><<<dim3(4, 1, BATCH), 256, 0, stream>>>(
      Wq, Gbf, T1bf, 256, 256, 256, 256, 2, 0, 65536, 65536,
      0.f, nullptr, nullptr, nullptr, nullptr, 0);
  // S = (T1 * Wk^T + bias terms) * scale
  gemm_glds_kernel<2><<<dim3(4, 1, BATCH), 256, 0, stream>>>(
      T1bf, Wk, Sf, 256, 256, 256, 256, 2, 65536, 0, 65536,
      0.0625f, qkv_b, qkv_b + 256, uws, wws, 256);

  softmax_kernel<<<BATCH * C, 256, 0, stream>>>(Sf, attnT);

  // M = Pw * attn   (B operand = attn^T)
  gemm_glds_kernel<1><<<dim3(4, 1, BATCH), 256, 0, stream>>>(
      Pw, attnT, Mbf, 256, 256, 256, 256, 2, 0, 65536, 65536,
      0.f, nullptr, nullptr, nullptr, nullptr, 0);
  cbias_kernel<<<BATCH, 256, 0, stream>>>(Mbf, qkv_b, proj_b, cb);
  // W2 = M * Wv     (B operand = WvT)
  gemm_glds_kernel<1><<<dim3(4, 1, BATCH), 256, 0, stream>>>(
      Mbf, WvT, W2bf, 256, 256, 256, 256, 2, 65536, 0, 65536,
      0.f, nullptr, nullptr, nullptr, nullptr, 0);

  // fused conv + attention-output, single store of out
  convattn_kernel<<<dim3(64, BATCH), 256, 0, stream>>>(xT, cw, W2bf, zbuf,
                                                       conv_b, cb, out);
}